// Round 10
// baseline (714.332 us; speedup 1.0000x reference)
//
#include <hip/hip_runtime.h>
#include <hip/hip_bf16.h>
#include <stdint.h>

#define M_TOTAL 16384
#define N_TOTAL 4096
#define K_TOTAL 4096
#define NT32 (K_TOTAL / 32)    // 128 K-steps of 32

typedef __attribute__((ext_vector_type(8))) short bf16x8;
typedef __attribute__((ext_vector_type(4))) float f32x4;

__device__ __forceinline__ void gload_lds16(const void* g, void* l) {
    __builtin_amdgcn_global_load_lds(
        (const __attribute__((address_space(1))) uint32_t*)g,
        (__attribute__((address_space(3))) uint32_t*)l, 16, 0, 0);
}

// ---------------------------------------------------------------------------
// Kernel 0: X f32 -> bf16.
// ---------------------------------------------------------------------------
__global__ __launch_bounds__(256) void k_convX(const float* __restrict__ X,
                                               __hip_bfloat16* __restrict__ Xb) {
    size_t t = (size_t)blockIdx.x * 256 + threadIdx.x;
    const float* p = X + t * 8;
    float4 a = *(const float4*)p;
    float4 b = *(const float4*)(p + 4);
    __hip_bfloat162 o[4] = {
        __float22bfloat162_rn(make_float2(a.x, a.y)),
        __float22bfloat162_rn(make_float2(a.z, a.w)),
        __float22bfloat162_rn(make_float2(b.x, b.y)),
        __float22bfloat162_rn(make_float2(b.z, b.w))};
    *(int4*)(Xb + t * 8) = *(int4*)&o[0];
}

// ---------------------------------------------------------------------------
// Kernel 1: packed int4 -> bf16 W[N][K].
// ---------------------------------------------------------------------------
__global__ __launch_bounds__(256) void k_dequant(const int* __restrict__ pw,
                                                 const float* __restrict__ sc,
                                                 __hip_bfloat16* __restrict__ W) {
    int t = blockIdx.x * 256 + threadIdx.x;
    int row = t >> 8;
    int w0 = (t & 255) << 3;
    const int* p = pw + (size_t)row * 2048 + w0;
    int4 q0 = *(const int4*)p;
    int4 q1 = *(const int4*)(p + 4);
    float s = sc[row * 128 + (w0 >> 4)];
    float ns8 = -8.0f * s;
    int w[8] = {q0.x, q0.y, q0.z, q0.w, q1.x, q1.y, q1.z, q1.w};
    __hip_bfloat162 o[8];
#pragma unroll
    for (int i = 0; i < 8; ++i) {
        float lo = fmaf((float)(w[i] & 15), s, ns8);
        float hi = fmaf((float)(w[i] >> 4), s, ns8);
        o[i] = __float22bfloat162_rn(make_float2(lo, hi));
    }
    __hip_bfloat16* dst = W + (size_t)row * 4096 + w0 * 2;
    *(int4*)dst = *(int4*)&o[0];
    *(int4*)(dst + 8) = *(int4*)&o[4];
}

// ---------------------------------------------------------------------------
// Kernel 2 (tier A): 256x256 tile, BK=32, RING-4 LDS (4 x 32KB = 128KB),
// 8 waves (2Mx4N), per-wave 128x64, mfma 16x16x32.
//
// ROUND 10: ds_reads issued ONE PHASE BEFORE their MFMA (the r8/r9 stall was
// the same-phase read burst: LDS serves 96KB before any MFMA can start).
// Ring-4 makes cross-step pre-issue legal: buf[s+1] is published at step-s
// entry barrier.
//
// Steady-state step s (ONE barrier):
//   P1: stage B-h0(s+2); issue ds A_hi(s);      MFMA Q1 = A_lo(s) x B(s)
//   P2: stage B-h1(s+2); issue ds A_lo(s+1),B(s+1) [buf s+1, published];
//                                               MFMA Q2 = A_hi(s) x B(s)
//   stage A-h0,h1(s+3); VMW(2); BAR
// vmcnt ledger at boundary (in order): [s+2:i1,i2 (entry), s+2:i3 (P1),
// s+2:i4 (P2), s+3:i1,i2] = 6 -> vmcnt(2) drains ALL of tile s+2, leaves
// s+3's 2. Tile T publish: boundary of step T-2; first read: P2(T-1). OK.
// Buffer overwrite: buf[(s+2)%4] = buf[(s-2)%4]; its reads COMPLETED
// (lgkm-waited) in step s-2, >=1 boundary BAR before earliest write (P2(s-1)).
// B regs double-buffered (B0/B1 by name); A_lo/A_hi reissued after last use.
// Compiler emits counted lgkmcnt from reg deps; sched_barrier(0) pins
// issue-before-MFMA order.
//
// LDS layout: r6-verified 0-conflict slot scheme (64B rows): 16B slot =
// chunk*8 + row%8 per 8-row group; linear gload dest, permuted global src.
// ---------------------------------------------------------------------------
__global__ __launch_bounds__(512, 2) void k_gemm10(const __hip_bfloat16* __restrict__ Xb,
                                                   const __hip_bfloat16* __restrict__ Wb,
                                                   float* __restrict__ out) {
    __shared__ __align__(16) short L[4][2][8192];   // [buf][A/B][16KB]

    int bid = blockIdx.x;
    int swz = (bid & 7) * 128 + (bid >> 3);         // XCD-bijective (1024%8==0)
    int bn = swz & 15, bm = swz >> 4;
    int m0 = bm * 256, n0 = bn * 256;
    int t = threadIdx.x, lane = t & 63, wv = t >> 6;
    int wm = wv >> 2, wn = wv & 3;

    // staging source (r6 scheme): thread t -> row (t>>5)*8+(t&7), chunk (t>>3)&3
    int srow = (t >> 5) * 8 + (t & 7);
    int scol = ((t >> 3) & 3) * 8;
    const __hip_bfloat16* gA = Xb + (size_t)(m0 + srow) * K_TOTAL + scol;
    const __hip_bfloat16* gB = Wb + (size_t)(n0 + srow) * K_TOTAL + scol;

    // stage helpers: tile T (K-cols T*32..T*32+31)
    auto stA_both = [&](int b, int T) {   // A rows 0-127 and 128-255 (i1,i2)
        gload_lds16(gA + T * 32, &L[b][0][t * 8]);
        gload_lds16(gA + (size_t)128 * K_TOTAL + T * 32, &L[b][0][4096 + t * 8]);
    };
    auto stB_half = [&](int b, int h, int T) {  // B rows h*128..h*128+127 (i3/i4)
        gload_lds16(gB + (size_t)(h * 128) * K_TOTAL + T * 32, &L[b][1][h * 4096 + t * 8]);
    };

    // frag-read lane offset (shorts): row r=R+(lane&15), chunk lane>>4
    const int offL = ((lane & 15) >> 3) * 256 + ((lane >> 4) * 8 + (lane & 7)) * 8;

    f32x4 acc[8][4];
#pragma unroll
    for (int f = 0; f < 8; ++f)
#pragma unroll
        for (int j = 0; j < 4; ++j) acc[f][j] = (f32x4)(0.0f);

    bf16x8 A_lo[4], A_hi[4], B0[4], B1[4];

#define RD_AH(S) { const short* LAx = &L[(S) & 3][0][0]; _Pragma("unroll") \
    for (int rf = 0; rf < 4; ++rf) \
        A_hi[rf] = *(const bf16x8*)&LAx[(wm * 128 + 64 + rf * 16) * 32 + offL]; }
#define RD_ALB(S, BN) { const short* LAx = &L[(S) & 3][0][0]; \
    const short* LBx = &L[(S) & 3][1][0]; _Pragma("unroll") \
    for (int rf = 0; rf < 4; ++rf) \
        A_lo[rf] = *(const bf16x8*)&LAx[(wm * 128 + rf * 16) * 32 + offL]; \
    _Pragma("unroll") \
    for (int cf = 0; cf < 4; ++cf) \
        BN[cf] = *(const bf16x8*)&LBx[(wn * 64 + cf * 16) * 32 + offL]; }
#define MMQ(RB, AV, BV) { _Pragma("unroll") for (int rf = 0; rf < 4; ++rf) \
    _Pragma("unroll") for (int cf = 0; cf < 4; ++cf) \
        acc[(RB) + rf][cf] = __builtin_amdgcn_mfma_f32_16x16x32_bf16( \
            AV[rf], BV[cf], acc[(RB) + rf][cf], 0, 0, 0); }
#define BAR __builtin_amdgcn_s_barrier()
#define PRI(x) __builtin_amdgcn_s_setprio(x)
#define SB0 __builtin_amdgcn_sched_barrier(0)
#define VMW2 { asm volatile("s_waitcnt vmcnt(2)" ::: "memory"); SB0; }
#define VMW0 { asm volatile("s_waitcnt vmcnt(0)" ::: "memory"); SB0; }

#define STEP(S, BC, BN)                                                        \
    {                                                                          \
        const int s_ = (S);                                                    \
        /* P1 */                                                               \
        if (s_ + 2 < NT32) stB_half((s_ + 2) & 3, 0, s_ + 2);                  \
        RD_AH(s_)                                                              \
        SB0;                                                                   \
        PRI(1); MMQ(0, A_lo, BC) PRI(0);                                       \
        SB0;                                                                   \
        /* P2 */                                                               \
        if (s_ + 2 < NT32) stB_half((s_ + 2) & 3, 1, s_ + 2);                  \
        if (s_ + 1 < NT32) { RD_ALB(s_ + 1, BN) }                              \
        SB0;                                                                   \
        PRI(1); MMQ(4, A_hi, BC) PRI(0);                                       \
        SB0;                                                                   \
        if (s_ + 3 < NT32) stA_both((s_ + 3) & 3, s_ + 3);                     \
        if (s_ + 3 < NT32) { VMW2 } else { VMW0 }                              \
        BAR;                                                                   \
    }

    // ---- prologue: t0 full, t1 full, t2 A-halves (10 gloads) ----
    stA_both(0, 0); stB_half(0, 0, 0); stB_half(0, 1, 0);
    stA_both(1, 1); stB_half(1, 0, 1); stB_half(1, 1, 1);
    stA_both(2, 2);
    VMW2;            // drains t0,t1 (8 oldest), leaves t2's 2
    BAR;
    RD_ALB(0, B0)    // prime step-0 operands

    for (int s2 = 0; s2 < NT32 / 2; ++s2) {
        STEP(2 * s2, B0, B1);
        STEP(2 * s2 + 1, B1, B0);
    }
#undef STEP
#undef RD_AH
#undef RD_ALB
#undef MMQ
#undef BAR
#undef PRI
#undef SB0
#undef VMW2
#undef VMW0

    // ---- epilogue: C/D layout col=lane&15, row=(lane>>4)*4+reg ----
    int col0 = n0 + wn * 64 + (lane & 15);
    int row0 = m0 + wm * 128 + (lane >> 4) * 4;
#pragma unroll
    for (int f = 0; f < 8; ++f)
#pragma unroll
        for (int j = 0; j < 4; ++j) {
            f32x4 v = acc[f][j];
            int r = row0 + f * 16;
            int c = col0 + j * 16;
#pragma unroll
            for (int q = 0; q < 4; ++q)
                out[(size_t)(r + q) * N_TOTAL + c] = v[q];
        }
}

// ---------------------------------------------------------------------------
// Tier B: m97-structure GEMM, A reg-staged from f32 X (round-5 verified).
// ---------------------------------------------------------------------------
__global__ __launch_bounds__(256) void k_gemm2b(const float* __restrict__ X,
                                                const __hip_bfloat16* __restrict__ Wb,
                                                float* __restrict__ out) {
    __shared__ __align__(16) short As[128 * 32];
    __shared__ __align__(16) short Bs[128 * 32];
    int bid = blockIdx.x;
    int swz = (bid & 7) * 512 + (bid >> 3);
    int bn = swz & 31, bm = swz >> 5;
    int m0 = bm * 128, n0 = bn * 128;
    int t = threadIdx.x, lane = t & 63, wv = t >> 6;
    int wr = wv >> 1, wc = wv & 1;
    f32x4 acc[4][4];
#pragma unroll
    for (int i = 0; i < 4; ++i)
#pragma unroll
        for (int j = 0; j < 4; ++j) acc[i][j] = (f32x4)(0.0f);
    int arow = t >> 2, acol = (t & 3) * 8;
    const float* Agf0 = X + (size_t)(m0 + arow) * K_TOTAL + acol;
    const float* Agf1 = Agf0 + (size_t)64 * K_TOTAL;
    const __hip_bfloat16* Bg0 = Wb + (size_t)(n0 + arow) * K_TOTAL + acol;
    const __hip_bfloat16* Bg1 = Bg0 + (size_t)64 * K_TOTAL;
    float4 xa0 = *(const float4*)(Agf0), xa1 = *(const float4*)(Agf0 + 4);
    float4 xb0 = *(const float4*)(Agf1), xb1 = *(const float4*)(Agf1 + 4);
    for (int kt = 0; kt < NT32; ++kt) {
        if (kt) __syncthreads();
        __hip_bfloat162 oa[4] = {
            __float22bfloat162_rn(make_float2(xa0.x, xa0.y)),
            __float22bfloat162_rn(make_float2(xa0.z, xa0.w)),
            __float22bfloat162_rn(make_float2(xa1.x, xa1.y)),
            __float22bfloat162_rn(make_float2(xa1.z, xa1.w))};
        __hip_bfloat162 ob[4] = {
            __float22bfloat162_rn(make_float2(xb0.x, xb0.y)),
            __float22bfloat162_rn(make_float2(xb0.z, xb0.w)),
            __float22bfloat162_rn(make_float2(xb1.x, xb1.y)),
            __float22bfloat162_rn(make_float2(xb1.z, xb1.w))};
        *(int4*)&As[t * 8] = *(int4*)&oa[0];
        *(int4*)&As[2048 + t * 8] = *(int4*)&ob[0];
        gload_lds16(Bg0 + kt * 32, &Bs[t * 8]);
        gload_lds16(Bg1 + kt * 32, &Bs[2048 + t * 8]);
        __syncthreads();
        if (kt < NT32 - 1) {
            int ko = (kt + 1) * 32;
            xa0 = *(const float4*)(Agf0 + ko);
            xa1 = *(const float4*)(Agf0 + ko + 4);
            xb0 = *(const float4*)(Agf1 + ko);
            xb1 = *(const float4*)(Agf1 + ko + 4);
        }
        bf16x8 a[4], b[4];
        int ro = (lane & 15) * 32 + (lane >> 4) * 8;
#pragma unroll
        for (int i = 0; i < 4; ++i)
            a[i] = *(const bf16x8*)&As[(wr * 64 + i * 16) * 32 + ro];
#pragma unroll
        for (int j = 0; j < 4; ++j)
            b[j] = *(const bf16x8*)&Bs[(wc * 64 + j * 16) * 32 + ro];
#pragma unroll
        for (int i = 0; i < 4; ++i)
#pragma unroll
            for (int j = 0; j < 4; ++j)
                acc[i][j] = __builtin_amdgcn_mfma_f32_16x16x32_bf16(a[i], b[j], acc[i][j], 0, 0, 0);
    }
    int col0 = n0 + wc * 64 + (lane & 15);
    int row0 = m0 + wr * 64 + (lane >> 4) * 4;
#pragma unroll
    for (int i = 0; i < 4; ++i)
#pragma unroll
        for (int j = 0; j < 4; ++j) {
            f32x4 v = acc[i][j];
            int r = row0 + i * 16, c = col0 + j * 16;
#pragma unroll
            for (int q = 0; q < 4; ++q)
                out[(size_t)(r + q) * N_TOTAL + c] = v[q];
        }
}

extern "C" void kernel_launch(void* const* d_in, const int* in_sizes, int n_in,
                              void* d_out, int out_size, void* d_ws, size_t ws_size,
                              hipStream_t stream) {
    const float* X = (const float*)d_in[0];
    const int* PW = (const int*)d_in[1];
    const float* SC = (const float*)d_in[2];
    float* OUT = (float*)d_out;

    const size_t needW = (size_t)N_TOTAL * K_TOTAL * 2;            // 33.5 MB
    const size_t needX = needW + (size_t)M_TOTAL * K_TOTAL * 2;    // +134 MB

    if (ws_size >= needX) {
        __hip_bfloat16* Wb = (__hip_bfloat16*)d_ws;
        __hip_bfloat16* Xb = (__hip_bfloat16*)((char*)d_ws + needW);
        k_convX<<<dim3(32768), dim3(256), 0, stream>>>(X, Xb);
        k_dequant<<<dim3(4096), dim3(256), 0, stream>>>(PW, SC, Wb);
        k_gemm10<<<dim3((M_TOTAL / 256) * (N_TOTAL / 256)), dim3(512), 0, stream>>>(Xb, Wb, OUT);
    } else if (ws_size >= needW) {
        __hip_bfloat16* Wb = (__hip_bfloat16*)d_ws;
        k_dequant<<<dim3(4096), dim3(256), 0, stream>>>(PW, SC, Wb);
        k_gemm2b<<<dim3((M_TOTAL / 128) * (N_TOTAL / 128)), dim3(256), 0, stream>>>(X, Wb, OUT);
    }
}